// Round 4
// baseline (403.722 us; speedup 1.0000x reference)
//
#include <hip/hip_runtime.h>
#include <cstdint>
#include <cstddef>

#define NN 8192
#define FIN 128
#define FOUT 64
#define BM 16                 // rows per attn block
#define BN 64                 // cols per chunk
#define NCHUNK (NN / BN)      // 128 chunks (full row sweep -> no j-split partials)
#define LDP 72                // padded LDS row (bf16 elems)
#define PBM 32                // prep rows per block
#define NPREP (NN / PBM)      // 256 prep blocks

typedef __bf16 bf16x8 __attribute__((ext_vector_type(8)));
typedef unsigned short u16x8 __attribute__((ext_vector_type(8)));
typedef float f32x4 __attribute__((ext_vector_type(4)));

__device__ __forceinline__ unsigned short f2bf(float f) {
    unsigned u = __float_as_uint(f);
    u += 0x7FFFu + ((u >> 16) & 1u);   // RNE
    return (unsigned short)(u >> 16);
}
__device__ __forceinline__ float bf2f(unsigned short b) {
    return __uint_as_float(((unsigned)b) << 16);
}

// ---------------------------------------------------------------------------
// Kernel 1: prep. Per block: 32 rows.
//  - s1/s2 via exact-path fp32 dot with wa = W@a
//  - Ht[t][i] = bf16((x@W)[i][t]) via MFMA
//  - per-block s2 max written to pbmax[block] (no atomic, no init needed)
// ---------------------------------------------------------------------------
__global__ __launch_bounds__(256) void gat_prep(
    const float* __restrict__ x, const float* __restrict__ W,
    const float* __restrict__ a, float* __restrict__ s1,
    float* __restrict__ s2, unsigned short* __restrict__ Ht,
    float* __restrict__ pbmax)
{
    __shared__ __align__(16) float Wt[FOUT][FIN + 4];
    __shared__ float wa1[FIN], wa2[FIN];
    __shared__ float ash[2 * FOUT];
    __shared__ float s2sh[PBM];

    const int tid = threadIdx.x;
    const int i0 = blockIdx.x * PBM;

    for (int it = 0; it < 32; ++it) {
        int idx = it * 256 + tid;
        int k = idx >> 6, t = idx & 63;
        Wt[t][k] = W[idx];
    }
    if (tid < 2 * FOUT) ash[tid] = a[tid];
    __syncthreads();

    if (tid < FIN) {
        int k = tid;
        float acc = 0.f;
        #pragma unroll 8
        for (int t = 0; t < FOUT; ++t) acc = fmaf(Wt[t][k], ash[t], acc);
        wa1[k] = acc;
    } else {
        int k = tid - FIN;
        float acc = 0.f;
        #pragma unroll 8
        for (int t = 0; t < FOUT; ++t) acc = fmaf(Wt[t][k], ash[FOUT + t], acc);
        wa2[k] = acc;
    }
    __syncthreads();

    {
        int r = tid >> 3;
        int seg = tid & 7;
        const float* xp = x + (size_t)(i0 + r) * FIN + seg * 16;
        float d1 = 0.f, d2 = 0.f;
        #pragma unroll
        for (int m = 0; m < 16; ++m) {
            float xv = xp[m];
            d1 = fmaf(xv, wa1[seg * 16 + m], d1);
            d2 = fmaf(xv, wa2[seg * 16 + m], d2);
        }
        #pragma unroll
        for (int mk = 1; mk < 8; mk <<= 1) {
            d1 += __shfl_xor(d1, mk);
            d2 += __shfl_xor(d2, mk);
        }
        if (seg == 0) {
            s1[i0 + r] = d1;
            s2[i0 + r] = d2;
            s2sh[r] = d2;
        }
    }

    {
        const int lane = tid & 63;
        const int wv = tid >> 6;
        const int ih = wv & 1, nh = wv >> 1;
        const int m = lane & 15, quad = lane >> 4;
        f32x4 hacc0 = {0.f, 0.f, 0.f, 0.f};
        f32x4 hacc1 = {0.f, 0.f, 0.f, 0.f};
        const float* xrow = x + (size_t)(i0 + ih * 16 + m) * FIN + quad * 8;
        #pragma unroll
        for (int ks = 0; ks < 4; ++ks) {
            const float* xp = xrow + ks * 32;
            u16x8 ua;
            #pragma unroll
            for (int jj = 0; jj < 8; ++jj) ua[jj] = f2bf(xp[jj]);
            bf16x8 af = __builtin_bit_cast(bf16x8, ua);
            {
                const float* wp = &Wt[nh * 32 + m][ks * 32 + quad * 8];
                u16x8 ub;
                #pragma unroll
                for (int jj = 0; jj < 8; ++jj) ub[jj] = f2bf(wp[jj]);
                bf16x8 bfr = __builtin_bit_cast(bf16x8, ub);
                hacc0 = __builtin_amdgcn_mfma_f32_16x16x32_bf16(af, bfr, hacc0, 0, 0, 0);
            }
            {
                const float* wp = &Wt[nh * 32 + 16 + m][ks * 32 + quad * 8];
                u16x8 ub;
                #pragma unroll
                for (int jj = 0; jj < 8; ++jj) ub[jj] = f2bf(wp[jj]);
                bf16x8 bfr = __builtin_bit_cast(bf16x8, ub);
                hacc1 = __builtin_amdgcn_mfma_f32_16x16x32_bf16(af, bfr, hacc1, 0, 0, 0);
            }
        }
        #pragma unroll
        for (int reg = 0; reg < 4; ++reg) {
            int irow = i0 + ih * 16 + quad * 4 + reg;
            int t0 = nh * 32 + m;
            Ht[(size_t)t0 * NN + irow] = f2bf(hacc0[reg]);
            Ht[(size_t)(t0 + 16) * NN + irow] = f2bf(hacc1[reg]);
        }
    }
    __syncthreads();
    if (tid == 0) {
        float mx = s2sh[0];
        #pragma unroll
        for (int r = 1; r < PBM; ++r) mx = fmaxf(mx, s2sh[r]);
        pbmax[blockIdx.x] = mx;   // unconditional write -> no init/atomic needed
    }
}

// ---------------------------------------------------------------------------
// Kernel 2: fused masked-softmax + PV matmul, FULL row sweep (no j-split).
// 512 blocks x 16 rows; writes final out = acc / l directly.
// ---------------------------------------------------------------------------
__global__ __launch_bounds__(256, 2) void gat_attn(
    const int* __restrict__ adj, const float* __restrict__ s1,
    const float* __restrict__ s2, const unsigned short* __restrict__ Ht,
    const float* __restrict__ pbmax, float* __restrict__ out)
{
    __shared__ __align__(16) unsigned short p_lds[2][BM][LDP];   // 4.6 KB
    __shared__ __align__(16) float s2sh[NN];                     // 32 KB
    __shared__ float s1v[BM], lsum[BM];
    __shared__ float s2m;

    const int tid = threadIdx.x;
    const int i0 = blockIdx.x * BM;

    const int li = tid >> 4;          // 0..15: row handled by this thread
    const int jg = (tid & 15) * 4;    // col group within chunk

    const int* adjp = adj + (size_t)(i0 + li) * NN + jg;
    int4 ca = *(const int4*)adjp;     // prologue adj load (chunk 0)

    const int lane = tid & 63;
    const int wv = tid >> 6;          // 0..3: N-tile (output cols wv*16..+15)
    const int cm = lane & 15, quad = lane >> 4;

    const unsigned short* htb = Ht + (size_t)(wv * 16 + cm) * NN + quad * 8;

    // stage s2 strip (32 KB), global s2max from pbmax, s1 for our 16 rows
    #pragma unroll
    for (int it = 0; it < 8; ++it) {
        int idx = (it * 256 + tid) * 4;
        *(float4*)&s2sh[idx] = *(const float4*)(s2 + idx);
    }
    if (tid < 64) {
        float v = pbmax[tid];
        v = fmaxf(v, pbmax[tid + 64]);
        v = fmaxf(v, pbmax[tid + 128]);
        v = fmaxf(v, pbmax[tid + 192]);
        #pragma unroll
        for (int mk = 1; mk < 64; mk <<= 1) v = fmaxf(v, __shfl_xor(v, mk));
        if (tid == 0) s2m = v;
    }
    if (tid < BM) s1v[tid] = s1[i0 + tid];
    __syncthreads();

    const float S2MAX = s2m;
    const float s1a = s1v[li];
    const float Ma = fmaxf(0.f, s1a + S2MAX);   // upper bound of row max of e

    f32x4 acc = {0.f, 0.f, 0.f, 0.f};
    float ps = 0.f;                             // row-sum partial (register)

    #pragma unroll 2
    for (int c = 0; c < NCHUNK; ++c) {
        const int buf = c & 1;

        // this chunk's Ht B-fragments (L2-resident), consumed post-barrier
        bf16x8 b0 = *(const bf16x8*)(htb + c * BN);
        bf16x8 b1 = *(const bf16x8*)(htb + c * BN + 32);

        // next chunk's adj (HBM stream)
        const int cn = (c + 1 < NCHUNK) ? (c + 1) : c;
        int4 na = *(const int4*)(adjp + cn * BN);

        // compute p (bf16) into buf + accumulate register row-sum
        {
            const int* av = (const int*)&ca;
            const float* s2v = &s2sh[c * BN + jg];
            unsigned short q[4];
            #pragma unroll
            for (int jj = 0; jj < 4; ++jj) {
                float e = fmaxf(s1a + s2v[jj], 0.f);
                float p = (av[jj] > 0) ? __expf(e - Ma) : 0.f;
                q[jj] = f2bf(p);
                ps += bf2f(q[jj]);
            }
            *(ushort4*)&p_lds[buf][li][jg] = make_ushort4(q[0], q[1], q[2], q[3]);
        }

        __syncthreads();   // p_lds[buf] visible; drains vm loads above

        // PV MFMA: 16 rows x 16 cols per wave, K=64 in 2 steps
        {
            bf16x8 af0 = *(const bf16x8*)&p_lds[buf][cm][quad * 8];
            bf16x8 af1 = *(const bf16x8*)&p_lds[buf][cm][32 + quad * 8];
            acc = __builtin_amdgcn_mfma_f32_16x16x32_bf16(af0, b0, acc, 0, 0, 0);
            acc = __builtin_amdgcn_mfma_f32_16x16x32_bf16(af1, b1, acc, 0, 0, 0);
        }

        ca = na;
    }

    // complete row sums: reduce ps across the 16 lanes sharing a row
    #pragma unroll
    for (int mk = 1; mk < 16; mk <<= 1) ps += __shfl_xor(ps, mk);
    if ((tid & 15) == 0) lsum[li] = ps;
    __syncthreads();

    // epilogue: out = acc / l   (C layout: row = quad*4+reg, col = wv*16+cm)
    #pragma unroll
    for (int reg = 0; reg < 4; ++reg) {
        int row = quad * 4 + reg;
        out[(size_t)(i0 + row) * FOUT + wv * 16 + cm] = acc[reg] / lsum[row];
    }
}

// ---------------------------------------------------------------------------
extern "C" void kernel_launch(void* const* d_in, const int* in_sizes, int n_in,
                              void* d_out, int out_size, void* d_ws, size_t ws_size,
                              hipStream_t stream) {
    const float* x   = (const float*)d_in[0];
    const int*   adj = (const int*)d_in[1];
    const float* W   = (const float*)d_in[2];
    const float* a   = (const float*)d_in[3];
    float* out = (float*)d_out;

    char* ws = (char*)d_ws;
    float* s1          = (float*)(ws);                    // 32 KB
    float* s2          = (float*)(ws + 32768);            // 32 KB
    float* pbmax       = (float*)(ws + 65536);            // 1 KB
    unsigned short* Ht = (unsigned short*)(ws + 66560);   // 1 MiB

    gat_prep<<<NPREP, 256, 0, stream>>>(x, W, a, s1, s2, Ht, pbmax);
    gat_attn<<<NN / BM, 256, 0, stream>>>(adj, s1, s2, Ht, pbmax, out);
}